// Round 1
// baseline (8652.838 us; speedup 1.0000x reference)
//
#include <hip/hip_runtime.h>
#include <cstdint>
#include <cstddef>

// Problem constants (LSTM_62173946577315): T=256, B=128, E=1024, H=1024.
#define Tn 256
#define Bn 128
#define En 1024
#define Hn 1024
#define NG 4096   // 4*H gate rows, order [g,i,f,o]
#define Kh 1024   // K for the h-GEMM

typedef __bf16 bf16;
typedef __bf16 bf16x8 __attribute__((ext_vector_type(8)));
typedef __bf16 bf16x4 __attribute__((ext_vector_type(4)));
typedef float  f32x4  __attribute__((ext_vector_type(4)));

__device__ __forceinline__ float sigmoidf_(float x) {
  return 1.0f / (1.0f + __expf(-x));
}

// ---------------------------------------------------------------------------
// prep_w: split W_* (H x (E+H)) fp32 into Wx[4][H][E], Wh[4][H][H] bf16
// (row-major over k) and concatenate biases into bias[4096] fp32.
// ---------------------------------------------------------------------------
__global__ __launch_bounds__(256) void prep_w(
    const float* __restrict__ Wg, const float* __restrict__ Wi,
    const float* __restrict__ Wf, const float* __restrict__ Wo,
    const float* __restrict__ bg, const float* __restrict__ bi,
    const float* __restrict__ bff, const float* __restrict__ bo,
    bf16* __restrict__ Wx, bf16* __restrict__ Wh, float* __restrict__ bias)
{
  int idx = blockIdx.x * 256 + threadIdx.x;   // 0 .. 4*1024*1024-1
  int g = idx >> 20;
  int r = idx & 0xFFFFF;                      // u*1024 + k
  int u = r >> 10;
  int k = r & 1023;
  const float* Ws = (g == 0) ? Wg : (g == 1) ? Wi : (g == 2) ? Wf : Wo;
  size_t src = (size_t)u * (En + Hn) + k;
  Wx[idx] = (bf16)Ws[src];        // x-part: cols [0, E)
  Wh[idx] = (bf16)Ws[src + En];   // h-part: cols [E, E+H)
  if (idx < NG) {
    int gg = idx >> 10, uu = idx & 1023;
    const float* bs = (gg == 0) ? bg : (gg == 1) ? bi : (gg == 2) ? bff : bo;
    bias[idx] = bs[uu];
  }
}

// ---------------------------------------------------------------------------
// conv_x: embeds fp32 (T*B*E) -> bf16, vectorized x4.
// ---------------------------------------------------------------------------
__global__ __launch_bounds__(256) void conv_x(const float* __restrict__ X,
                                              bf16* __restrict__ Xb)
{
  int idx = blockIdx.x * 256 + threadIdx.x;   // per float4
  f32x4 v = ((const f32x4*)X)[idx];
  bf16x4 o;
  o[0] = (bf16)v[0]; o[1] = (bf16)v[1]; o[2] = (bf16)v[2]; o[3] = (bf16)v[3];
  ((bf16x4*)Xb)[idx] = o;
}

// ---------------------------------------------------------------------------
// zx_gemm: ZX[m][n] = sum_k Xb[m+128][k] * Wx[n][k] + bias[n], m = (t-1)*128+b
// for t in [1,256). M=32640, N=4096, K=1024. bf16 in, fp32 accum, bf16 out.
// 64x64 block tile, 4 waves 2x2, each wave 32x32 via 2x2 mfma 16x16x32.
// Fragments loaded directly from global (16B/lane), no LDS this round.
// ---------------------------------------------------------------------------
__global__ __launch_bounds__(256) void zx_gemm(
    const bf16* __restrict__ Xb, const bf16* __restrict__ Wx,
    const float* __restrict__ bias, bf16* __restrict__ zx)
{
  const int tid  = threadIdx.x;
  const int lane = tid & 63;
  const int wave = tid >> 6;
  const int wm = wave >> 1, wn = wave & 1;
  const int l15 = lane & 15, lq = lane >> 4;
  const int n0 = blockIdx.x * 64 + wn * 32;
  const int m0 = blockIdx.y * 64 + wm * 32;

  const f32x4 zero4 = {0.f, 0.f, 0.f, 0.f};
  f32x4 acc[2][2] = {{zero4, zero4}, {zero4, zero4}};

  const bf16* Ap = Xb + ((size_t)(128 + m0 + l15)) * En + lq * 8;
  const bf16* Bp = Wx + ((size_t)(n0 + l15)) * En + lq * 8;

  #pragma unroll 4
  for (int kc = 0; kc < En / 32; ++kc) {
    bf16x8 a0 = *(const bf16x8*)(Ap + kc * 32);
    bf16x8 a1 = *(const bf16x8*)(Ap + (size_t)16 * En + kc * 32);
    bf16x8 b0 = *(const bf16x8*)(Bp + kc * 32);
    bf16x8 b1 = *(const bf16x8*)(Bp + (size_t)16 * En + kc * 32);
    acc[0][0] = __builtin_amdgcn_mfma_f32_16x16x32_bf16(a0, b0, acc[0][0], 0, 0, 0);
    acc[0][1] = __builtin_amdgcn_mfma_f32_16x16x32_bf16(a0, b1, acc[0][1], 0, 0, 0);
    acc[1][0] = __builtin_amdgcn_mfma_f32_16x16x32_bf16(a1, b0, acc[1][0], 0, 0, 0);
    acc[1][1] = __builtin_amdgcn_mfma_f32_16x16x32_bf16(a1, b1, acc[1][1], 0, 0, 0);
  }

  #pragma unroll
  for (int mt = 0; mt < 2; ++mt)
    #pragma unroll
    for (int nt = 0; nt < 2; ++nt)
      #pragma unroll
      for (int i = 0; i < 4; ++i) {
        int m = m0 + mt * 16 + lq * 4 + i;   // C row = (lane>>4)*4 + reg
        int n = n0 + nt * 16 + l15;          // C col = lane&15
        zx[(size_t)m * NG + n] = (bf16)(acc[mt][nt][i] + bias[n]);
      }
}

// ---------------------------------------------------------------------------
// lstm_step: one timestep. Grid (64 unit-tiles x 2 batch-tiles), 256 threads.
// Wave w computes gate w's 64(batch) x 16(unit) z-tile:
//   z = h_prev @ Wh_g.T + zx.  Then LDS exchange -> fused gate elementwise.
// h ping-pong (other blocks read all of h_prev during the K loop).
// ---------------------------------------------------------------------------
__global__ __launch_bounds__(256) void lstm_step(
    const bf16* __restrict__ Wh,    // [4][H][K]
    const bf16* __restrict__ zxt,   // [B][4096] (bias included)
    const bf16* __restrict__ h_in,  // [B][H]
    bf16* __restrict__ h_out,       // [B][H]
    float* __restrict__ c,          // [B][H], in-place (per-(b,u) owner)
    float* __restrict__ out_t)      // [B][H] fp32
{
  const int tid  = threadIdx.x;
  const int lane = tid & 63;
  const int wave = tid >> 6;        // gate index g
  const int l15 = lane & 15;
  const int lq  = lane >> 4;
  const int u0 = blockIdx.x << 4;   // unit tile (16 units)
  const int b0 = blockIdx.y << 6;   // batch tile (64 rows)

  const f32x4 zero4 = {0.f, 0.f, 0.f, 0.f};
  f32x4 acc[4] = {zero4, zero4, zero4, zero4};

  const bf16* Bp = Wh + ((size_t)(wave * Hn + u0 + l15)) * Kh + lq * 8;
  const bf16* Ap = h_in + ((size_t)(b0 + l15)) * Hn + lq * 8;

  #pragma unroll 4
  for (int kc = 0; kc < Kh / 32; ++kc) {
    bf16x8 bfr = *(const bf16x8*)(Bp + kc * 32);
    #pragma unroll
    for (int mt = 0; mt < 4; ++mt) {
      bf16x8 afr = *(const bf16x8*)(Ap + (size_t)mt * 16 * Hn + kc * 32);
      acc[mt] = __builtin_amdgcn_mfma_f32_16x16x32_bf16(afr, bfr, acc[mt], 0, 0, 0);
    }
  }

  // Exchange z across gates via LDS, half the batch tile at a time (keeps
  // static LDS at 4*32*17*4 = 34.8 KB, +1 pad breaks power-of-2 strides).
  __shared__ float zs[4][32][17];
  #pragma unroll 1
  for (int half = 0; half < 2; ++half) {
    if (half) __syncthreads();      // protect LDS reuse (WAR)
    #pragma unroll
    for (int mtl = 0; mtl < 2; ++mtl) {
      int mt = half * 2 + mtl;
      #pragma unroll
      for (int i = 0; i < 4; ++i) {
        int browl = mtl * 16 + lq * 4 + i;            // 0..31 within half
        int b = b0 + half * 32 + browl;
        float zxv = (float)zxt[(size_t)b * NG + wave * Hn + u0 + l15];
        zs[wave][browl][l15] = acc[mt][i] + zxv;
      }
    }
    __syncthreads();
    for (int idx = tid; idx < 32 * 16; idx += 256) {
      int browl = idx >> 4;
      int col   = idx & 15;
      int b = b0 + half * 32 + browl;
      int u = u0 + col;
      float zg = zs[0][browl][col];
      float zi = zs[1][browl][col];
      float zf = zs[2][browl][col];
      float zo = zs[3][browl][col];
      float gv = tanhf(zg);
      float iv = sigmoidf_(zi);
      float fv = sigmoidf_(zf);
      float ov = sigmoidf_(zo);
      size_t off = (size_t)b * Hn + u;
      float cv = fv * c[off] + iv * gv;
      c[off] = cv;
      float hv = ov * tanhf(cv);
      out_t[off] = hv;
      h_out[off] = (bf16)hv;
    }
  }
}

// ---------------------------------------------------------------------------
// kernel_launch
// ---------------------------------------------------------------------------
extern "C" void kernel_launch(void* const* d_in, const int* in_sizes, int n_in,
                              void* d_out, int out_size, void* d_ws, size_t ws_size,
                              hipStream_t stream) {
  const float* embeds = (const float*)d_in[0];
  const float* Wg = (const float*)d_in[1];
  const float* Wi = (const float*)d_in[2];
  const float* Wf = (const float*)d_in[3];
  const float* Wo = (const float*)d_in[4];
  const float* bg = (const float*)d_in[5];
  const float* bi = (const float*)d_in[6];
  const float* bff = (const float*)d_in[7];
  const float* bo = (const float*)d_in[8];
  float* out = (float*)d_out;

  // Workspace carve (bytes; all 16B-aligned):
  //   Wx bf16  [4096][1024]          @ 0          (8,388,608)
  //   Wh bf16  [4096][1024]          @ 8388608    (8,388,608)
  //   bias f32 [4096]                @ 16777216   (16,384)
  //   Xb bf16  [256][128][1024]      @ 16793600   (67,108,864)
  //   zx bf16  [32640][4096]         @ 83902464   (267,386,880)
  //   h0 bf16  [128][1024]           @ 351289344  (262,144)
  //   h1 bf16  [128][1024]           @ 351551488  (262,144)
  //   c  f32   [128][1024]           @ 351813632  (524,288)
  // total = 352,337,920 bytes
  char* ws = (char*)d_ws;
  bf16*  Wx   = (bf16*)(ws + 0);
  bf16*  Wh   = (bf16*)(ws + 8388608);
  float* bias = (float*)(ws + 16777216);
  bf16*  Xb   = (bf16*)(ws + 16793600);
  bf16*  zx   = (bf16*)(ws + 83902464);
  bf16*  h0b  = (bf16*)(ws + 351289344);
  bf16*  h1b  = (bf16*)(ws + 351551488);
  float* cbuf = (float*)(ws + 351813632);

  // out[0] = h0 = zeros; zero h ping buffer and c.
  hipMemsetAsync(out, 0, (size_t)Bn * Hn * sizeof(float), stream);
  hipMemsetAsync(h0b, 0, (size_t)Bn * Hn * sizeof(bf16), stream);
  hipMemsetAsync(cbuf, 0, (size_t)Bn * Hn * sizeof(float), stream);

  prep_w<<<16384, 256, 0, stream>>>(Wg, Wi, Wf, Wo, bg, bi, bff, bo, Wx, Wh, bias);
  conv_x<<<32768, 256, 0, stream>>>(embeds, Xb);
  zx_gemm<<<dim3(64, 510), 256, 0, stream>>>(Xb, Wx, bias, zx);

  bf16* hb[2] = {h0b, h1b};
  for (int t = 1; t < Tn; ++t) {
    lstm_step<<<dim3(64, 2), 256, 0, stream>>>(
        Wh, zx + (size_t)(t - 1) * Bn * NG,
        hb[(t - 1) & 1], hb[t & 1], cbuf,
        out + (size_t)t * Bn * Hn);
  }
}

// Round 2
// 6528.075 us; speedup vs baseline: 1.3255x; 1.3255x over previous
//
#include <hip/hip_runtime.h>
#include <cstdint>
#include <cstddef>

// Problem constants (LSTM_62173946577315): T=256, B=128, E=1024, H=1024.
#define Tn 256
#define Bn 128
#define En 1024
#define Hn 1024
#define NG 4096   // 4*H gate rows, order [g,i,f,o]

typedef __bf16 bf16;
typedef __bf16 bf16x8 __attribute__((ext_vector_type(8)));
typedef __bf16 bf16x4 __attribute__((ext_vector_type(4)));
typedef float  f32x4  __attribute__((ext_vector_type(4)));

typedef __attribute__((address_space(1))) void gvoid;
typedef __attribute__((address_space(3))) void lvoid;

__device__ __forceinline__ float sigmoidf_(float x) {
  return 1.0f / (1.0f + __expf(-x));
}

// ---------------------------------------------------------------------------
// prep_w: split W_* (H x (E+H)) fp32 into Wx[4][H][E], Wh[4][H][H] bf16
// (row-major over k) and concatenate biases into bias[4096] fp32.
// ---------------------------------------------------------------------------
__global__ __launch_bounds__(256) void prep_w(
    const float* __restrict__ Wg, const float* __restrict__ Wi,
    const float* __restrict__ Wf, const float* __restrict__ Wo,
    const float* __restrict__ bg, const float* __restrict__ bi,
    const float* __restrict__ bff, const float* __restrict__ bo,
    bf16* __restrict__ Wx, bf16* __restrict__ Wh, float* __restrict__ bias)
{
  int idx = blockIdx.x * 256 + threadIdx.x;   // 0 .. 4*1024*1024-1
  int g = idx >> 20;
  int r = idx & 0xFFFFF;                      // u*1024 + k
  int u = r >> 10;
  int k = r & 1023;
  const float* Ws = (g == 0) ? Wg : (g == 1) ? Wi : (g == 2) ? Wf : Wo;
  size_t src = (size_t)u * (En + Hn) + k;
  Wx[idx] = (bf16)Ws[src];        // x-part: cols [0, E)
  Wh[idx] = (bf16)Ws[src + En];   // h-part: cols [E, E+H)
  if (idx < NG) {
    int gg = idx >> 10, uu = idx & 1023;
    const float* bs = (gg == 0) ? bg : (gg == 1) ? bi : (gg == 2) ? bff : bo;
    bias[idx] = bs[uu];
  }
}

// ---------------------------------------------------------------------------
// conv_x: embeds fp32 (T*B*E) -> bf16, vectorized x4.
// ---------------------------------------------------------------------------
__global__ __launch_bounds__(256) void conv_x(const float* __restrict__ X,
                                              bf16* __restrict__ Xb)
{
  int idx = blockIdx.x * 256 + threadIdx.x;   // per float4
  f32x4 v = ((const f32x4*)X)[idx];
  bf16x4 o;
  o[0] = (bf16)v[0]; o[1] = (bf16)v[1]; o[2] = (bf16)v[2]; o[3] = (bf16)v[3];
  ((bf16x4*)Xb)[idx] = o;
}

// ---------------------------------------------------------------------------
// zx_gemm: ZX[m][n] = sum_k Xb[m+128][k] * Wx[n][k] + bias[n], m = (t-1)*128+b
// for t in [1,256). M=32640, N=4096, K=1024. bf16 in, fp32 accum, bf16 out.
// ---------------------------------------------------------------------------
__global__ __launch_bounds__(256) void zx_gemm(
    const bf16* __restrict__ Xb, const bf16* __restrict__ Wx,
    const float* __restrict__ bias, bf16* __restrict__ zx)
{
  const int tid  = threadIdx.x;
  const int lane = tid & 63;
  const int wave = tid >> 6;
  const int wm = wave >> 1, wn = wave & 1;
  const int l15 = lane & 15, lq = lane >> 4;
  const int n0 = blockIdx.x * 64 + wn * 32;
  const int m0 = blockIdx.y * 64 + wm * 32;

  const f32x4 zero4 = {0.f, 0.f, 0.f, 0.f};
  f32x4 acc[2][2] = {{zero4, zero4}, {zero4, zero4}};

  const bf16* Ap = Xb + ((size_t)(128 + m0 + l15)) * En + lq * 8;
  const bf16* Bp = Wx + ((size_t)(n0 + l15)) * En + lq * 8;

  #pragma unroll 4
  for (int kc = 0; kc < En / 32; ++kc) {
    bf16x8 a0 = *(const bf16x8*)(Ap + kc * 32);
    bf16x8 a1 = *(const bf16x8*)(Ap + (size_t)16 * En + kc * 32);
    bf16x8 b0 = *(const bf16x8*)(Bp + kc * 32);
    bf16x8 b1 = *(const bf16x8*)(Bp + (size_t)16 * En + kc * 32);
    acc[0][0] = __builtin_amdgcn_mfma_f32_16x16x32_bf16(a0, b0, acc[0][0], 0, 0, 0);
    acc[0][1] = __builtin_amdgcn_mfma_f32_16x16x32_bf16(a0, b1, acc[0][1], 0, 0, 0);
    acc[1][0] = __builtin_amdgcn_mfma_f32_16x16x32_bf16(a1, b0, acc[1][0], 0, 0, 0);
    acc[1][1] = __builtin_amdgcn_mfma_f32_16x16x32_bf16(a1, b1, acc[1][1], 0, 0, 0);
  }

  #pragma unroll
  for (int mt = 0; mt < 2; ++mt)
    #pragma unroll
    for (int nt = 0; nt < 2; ++nt)
      #pragma unroll
      for (int i = 0; i < 4; ++i) {
        int m = m0 + mt * 16 + lq * 4 + i;   // C row = (lane>>4)*4 + reg
        int n = n0 + nt * 16 + l15;          // C col = lane&15
        zx[(size_t)m * NG + n] = (bf16)(acc[mt][nt][i] + bias[n]);
      }
}

// ---------------------------------------------------------------------------
// lstm_persist: the whole 255-step scan in ONE cooperative kernel.
// Grid 256 blocks x 256 threads (1 block/CU). Block = (unit-tile ut of 16,
// batch-quarter qb of 32 rows). Wave w = gate g, holding its Wh slice
// (16 n-rows x 1024 k) in 128 VGPRs for the whole kernel.
// Per step: stage h-tile (32x1024) -> LDS (shared by 4 waves), 64 MFMA/wave,
// LDS gate exchange, fused elementwise with c in registers, write h (ping-
// pong) + out fp32, device-scope barrier (fresh slot per step).
// ---------------------------------------------------------------------------
#define HS_STRIDE 1032   // 1024 + 8 bf16 pad -> 2064 B row stride (2-way banks)

__global__ __launch_bounds__(256, 1) void lstm_persist(
    const bf16* __restrict__ Wh,    // [4][1024][1024]
    const bf16* __restrict__ zx,    // [255*128][4096] (bias folded in)
    bf16* __restrict__ hb0,         // ping [128][1024]
    bf16* __restrict__ hb1,         // pong [128][1024]
    float* __restrict__ out,        // [256][128][1024]
    unsigned int* __restrict__ bar) // [256] zero-initialized barrier slots
{
  const int tid  = threadIdx.x;
  const int lane = tid & 63;
  const int g    = tid >> 6;         // wave index == gate
  const int l15  = lane & 15;
  const int lq   = lane >> 4;
  const int ut   = blockIdx.x & 63;  // unit tile (16 units)
  const int qb   = blockIdx.x >> 6;  // batch quarter (32 rows)

  __shared__ bf16  hs[32 * HS_STRIDE];   // 66,048 B
  __shared__ float zs[4][32][17];        //  8,704 B

  // --- Preload this wave's Wh slice into registers: 16 n x 1024 k ---------
  bf16x8 wfrag[32];
  {
    const bf16* wp = Wh + ((size_t)(g * Hn + ut * 16 + l15)) * Hn + lq * 8;
    #pragma unroll
    for (int ks = 0; ks < 32; ++ks)
      wfrag[ks] = *(const bf16x8*)(wp + ks * 32);
  }

  // --- Per-thread cell state: 2 cells (tid, tid+256) of the 32x16 tile ----
  float creg[2] = {0.f, 0.f};

  const f32x4 zero4 = {0.f, 0.f, 0.f, 0.f};

  for (int t = 1; t < Tn; ++t) {
    const bf16* hin = ((t - 1) & 1) ? hb1 : hb0;
    bf16*       hout = (t & 1) ? hb1 : hb0;

    // --- Stage h(t-1) block tile (32 rows x 1024 k) into LDS -------------
    // 64 half-rows of 1024 B; wave g handles half-rows [g*16, g*16+16).
    #pragma unroll
    for (int j = 0; j < 16; ++j) {
      int rh   = g * 16 + j;
      int row  = rh >> 1;
      int half = rh & 1;
      const bf16* src = hin + ((size_t)(qb * 32 + row)) * Hn + half * 512 + lane * 8;
      bf16* dst = &hs[row * HS_STRIDE + half * 512];
      __builtin_amdgcn_global_load_lds((const gvoid*)src, (lvoid*)dst, 16, 0, 0);
    }
    __syncthreads();   // staging complete (vmcnt(0) + barrier)

    // --- z partial = h_tile @ Wh_g^T : 2 mt x 32 ks MFMAs ----------------
    f32x4 acc[2] = {zero4, zero4};
    #pragma unroll
    for (int ks = 0; ks < 32; ++ks) {
      bf16x8 a0 = *(const bf16x8*)&hs[(l15) * HS_STRIDE + ks * 32 + lq * 8];
      bf16x8 a1 = *(const bf16x8*)&hs[(16 + l15) * HS_STRIDE + ks * 32 + lq * 8];
      acc[0] = __builtin_amdgcn_mfma_f32_16x16x32_bf16(a0, wfrag[ks], acc[0], 0, 0, 0);
      acc[1] = __builtin_amdgcn_mfma_f32_16x16x32_bf16(a1, wfrag[ks], acc[1], 0, 0, 0);
    }

    // --- Gate exchange through LDS ---------------------------------------
    #pragma unroll
    for (int mt = 0; mt < 2; ++mt)
      #pragma unroll
      for (int i = 0; i < 4; ++i)
        zs[g][mt * 16 + lq * 4 + i][l15] = acc[mt][i];
    __syncthreads();

    // --- Fused elementwise: 512 cells / 256 threads = 2 each -------------
    #pragma unroll
    for (int j = 0; j < 2; ++j) {
      int cell = tid + j * 256;        // 0..511
      int bl = cell >> 4;              // 0..31
      int ul = cell & 15;              // 0..15
      int b = qb * 32 + bl;
      int u = ut * 16 + ul;
      size_t zoff = ((size_t)(t - 1) * Bn + b) * NG;
      float zg = zs[0][bl][ul] + (float)zx[zoff + 0 * Hn + u];
      float zi = zs[1][bl][ul] + (float)zx[zoff + 1 * Hn + u];
      float zf = zs[2][bl][ul] + (float)zx[zoff + 2 * Hn + u];
      float zo = zs[3][bl][ul] + (float)zx[zoff + 3 * Hn + u];
      float gv = tanhf(zg);
      float iv = sigmoidf_(zi);
      float fv = sigmoidf_(zf);
      float ov = sigmoidf_(zo);
      float cv = fv * creg[j] + iv * gv;
      creg[j] = cv;
      float hv = ov * tanhf(cv);
      size_t off = (size_t)b * Hn + u;
      hout[off] = (bf16)hv;
      out[(size_t)t * Bn * Hn + off] = hv;
    }

    // --- Grid barrier: h(t) visible device-wide before step t+1 ----------
    __syncthreads();   // all threads' stores issued & complete (vmcnt drain)
    if (t < Tn - 1) {
      if (tid == 0) {
        __hip_atomic_fetch_add(&bar[t], 1u, __ATOMIC_RELEASE,
                               __HIP_MEMORY_SCOPE_AGENT);
        while (__hip_atomic_load(&bar[t], __ATOMIC_RELAXED,
                                 __HIP_MEMORY_SCOPE_AGENT) < 256u) {
          __builtin_amdgcn_s_sleep(8);
        }
        (void)__hip_atomic_load(&bar[t], __ATOMIC_ACQUIRE,
                                __HIP_MEMORY_SCOPE_AGENT);
      }
      __syncthreads();
    }
  }
}

// ---------------------------------------------------------------------------
// kernel_launch
// ---------------------------------------------------------------------------
extern "C" void kernel_launch(void* const* d_in, const int* in_sizes, int n_in,
                              void* d_out, int out_size, void* d_ws, size_t ws_size,
                              hipStream_t stream) {
  const float* embeds = (const float*)d_in[0];
  const float* Wg = (const float*)d_in[1];
  const float* Wi = (const float*)d_in[2];
  const float* Wf = (const float*)d_in[3];
  const float* Wo = (const float*)d_in[4];
  const float* bg = (const float*)d_in[5];
  const float* bi = (const float*)d_in[6];
  const float* bff = (const float*)d_in[7];
  const float* bo = (const float*)d_in[8];
  float* out = (float*)d_out;

  // Workspace carve (bytes; all >=16B-aligned):
  //   Wx bf16  [4096][1024]          @ 0          (8,388,608)
  //   Wh bf16  [4096][1024]          @ 8388608    (8,388,608)
  //   bias f32 [4096]                @ 16777216   (16,384)
  //   Xb bf16  [256][128][1024]      @ 16793600   (67,108,864)
  //   zx bf16  [32640][4096]         @ 83902464   (267,386,880)
  //   h0 bf16  [128][1024]           @ 351289344  (262,144)
  //   h1 bf16  [128][1024]           @ 351551488  (262,144)
  //   bar u32  [256]                 @ 351813632  (1,024)
  char* ws = (char*)d_ws;
  bf16*  Wx   = (bf16*)(ws + 0);
  bf16*  Wh   = (bf16*)(ws + 8388608);
  float* bias = (float*)(ws + 16777216);
  bf16*  Xb   = (bf16*)(ws + 16793600);
  bf16*  zx   = (bf16*)(ws + 83902464);
  bf16*  h0b  = (bf16*)(ws + 351289344);
  bf16*  h1b  = (bf16*)(ws + 351551488);
  unsigned int* bar = (unsigned int*)(ws + 351813632);

  // out[0] = h0 = zeros; zero h ping buffer and barrier slots.
  hipMemsetAsync(out, 0, (size_t)Bn * Hn * sizeof(float), stream);
  hipMemsetAsync(h0b, 0, (size_t)Bn * Hn * sizeof(bf16), stream);
  hipMemsetAsync(bar, 0, 256 * sizeof(unsigned int), stream);

  prep_w<<<16384, 256, 0, stream>>>(Wg, Wi, Wf, Wo, bg, bi, bff, bo, Wx, Wh, bias);
  conv_x<<<32768, 256, 0, stream>>>(embeds, Xb);
  zx_gemm<<<dim3(64, 510), 256, 0, stream>>>(Xb, Wx, bias, zx);

  void* args[] = {(void*)&Wh, (void*)&zx, (void*)&h0b, (void*)&h1b,
                  (void*)&out, (void*)&bar};
  hipLaunchCooperativeKernel((void*)lstm_persist, dim3(256), dim3(256),
                             args, 0, stream);
}